// Round 10
// baseline (594.595 us; speedup 1.0000x reference)
//
#include <hip/hip_runtime.h>
#include <hip/hip_bf16.h>

#define B_ 32
#define N_ 8192
#define DI_ 128
#define D_ 512
#define NC_ 1000
#define TN_ 128          // items per output tile (per block)
#define SN_ 16           // items per sub-tile (4-wave k_main)
#define NSUB_ 8          // sub-tiles per block
#define NT_ 64           // tiles = N_/TN_
#define XROW_ 136        // x_lds row stride in shorts (pad +8)

typedef short s8v __attribute__((ext_vector_type(8)));
typedef float f4v __attribute__((ext_vector_type(4)));

__device__ __forceinline__ unsigned short f2bf(float f){
  union { float f; unsigned u; } c; c.f = f;
  unsigned r = c.u + 0x7fffu + ((c.u >> 16) & 1u);
  return (unsigned short)(r >> 16);
}

__device__ __forceinline__ unsigned pk2bf(float a, float b){
  float2 f; f.x = a; f.y = b;
  __hip_bfloat162 h = __float22bfloat162_rn(f);
  union { __hip_bfloat162 h; unsigned u; } c; c.h = h;
  return c.u;
}

// exact GELU: 0.5x(1+erf(x/sqrt2)); Abramowitz-Stegun 7.1.26, |err| <= 1.5e-7
__device__ __forceinline__ float gelu_f(float x){
  float ax = fabsf(x) * 0.70710678118654752f;
  float t = __builtin_amdgcn_rcpf(1.0f + 0.3275911f * ax);
  float poly = ((((1.061405429f*t - 1.453152027f)*t + 1.421413741f)*t
                 - 0.284496736f)*t + 0.254829592f)*t;
  float e = __expf(-ax*ax);
  float erf_ax = 1.0f - poly*e;
  erf_ax = (x >= 0.0f) ? erf_ax : -erf_ax;
  return 0.5f * x * (1.0f + erf_ax);
}

__device__ __forceinline__ float wsum64(float v){
  #pragma unroll
  for (int off = 32; off; off >>= 1) v += __shfl_xor(v, off, 64);
  return v;
}

// ---------------- prep3: w1 pack + 2 transposes + 3 folded fp32 GEMMs (FROZEN from r9) ----------------
__global__ __launch_bounds__(512)
void k_prep3(const float* __restrict__ w1,  unsigned short* __restrict__ w1p,
             const float* __restrict__ pw1, float* __restrict__ pw1T,
             const float* __restrict__ pw2, float* __restrict__ pw2T,
             const float* __restrict__ kw,  const float* __restrict__ w2,
             float* __restrict__ KW2,
             const float* __restrict__ qw,  const float* __restrict__ w2q,
             const float* __restrict__ b2q, const float* __restrict__ qb,
             float* __restrict__ QW2qT,
             const float* __restrict__ vw,  const float* __restrict__ b2x,
             const float* __restrict__ vb,  float* __restrict__ VW2T){
  const int t = threadIdx.x;
  const int bid = blockIdx.x;
  __shared__ float As[64][65];
  __shared__ float Bs[64][68];
  __shared__ float bsv[64];

  if (bid < 128){
    const int i = bid*512 + t;
    const int j = i / DI_, kc = i % DI_;
    const int kk = kc >> 5, q = (kc >> 3) & 3, s = kc & 7;
    w1p[((kk*D_ + j)*4 + q)*8 + s] = f2bf(w1[i]);
    return;
  }
  const int r0 = t >> 6;
  const int c  = t & 63;
  if (bid < 192){                              // pw1 transpose
    const int id = bid - 128;
    const int to = id >> 3, tk = id & 7;
    #pragma unroll
    for (int i = 0; i < 8; ++i){
      const int r = r0 + i*8;
      As[r][c] = pw1[(size_t)(to*64 + r)*D_ + tk*64 + c];
    }
    __syncthreads();
    #pragma unroll
    for (int i = 0; i < 8; ++i){
      const int r = r0 + i*8;
      pw1T[(size_t)(tk*64 + r)*D_ + to*64 + c] = As[c][r];
    }
    return;
  }
  if (bid < 320){                              // pw2 transpose
    const int id = bid - 192;
    const int tr = id >> 3, tk = id & 7;
    #pragma unroll
    for (int i = 0; i < 8; ++i){
      const int r = r0 + i*8;
      const int ro = tr*64 + r;
      As[r][c] = (ro < NC_) ? pw2[(size_t)ro*D_ + tk*64 + c] : 0.f;
    }
    __syncthreads();
    #pragma unroll
    for (int i = 0; i < 8; ++i){
      const int r = r0 + i*8;
      const int co = tr*64 + c;
      if (co < NC_)
        pw2T[(size_t)(tk*64 + r)*NC_ + co] = As[c][r];
    }
    return;
  }
  // ---- GEMM blocks ----
  const int id = bid - 320;
  const int mi = id >> 6;                      // 0 KW2(NN), 1 QW2qT(TN), 2 VW2T(TN)
  const int tt = id & 63;
  const int rt = tt >> 3, ct = tt & 7;
  const float* A    = (mi==0) ? kw  : (mi==1) ? qw  : vw;
  const float* B    = (mi==1) ? w2q : w2;
  const float* bvec = (mi==1) ? b2q : b2x;
  const float* badd = (mi==1) ? qb  : vb;
  float* C          = (mi==0) ? KW2 : (mi==1) ? QW2qT : VW2T;
  const bool nn = (mi == 0);
  const int arow0 = (nn ? rt : ct) * 64;
  const int bcol0 = (nn ? ct : rt) * 64;

  float acc[8] = {0.f,0.f,0.f,0.f,0.f,0.f,0.f,0.f};
  float ba0 = 0.f, ba1 = 0.f;

  for (int i0 = 0; i0 < 512; i0 += 64){
    #pragma unroll
    for (int i = 0; i < 8; ++i){
      const int r = r0 + i*8;
      As[r][c] = A[(size_t)(arow0 + r)*512 + i0 + c];
      Bs[r][c] = B[(size_t)(i0 + r)*512 + bcol0 + c];
    }
    if (t < 64) bsv[t] = (mi != 0) ? bvec[i0 + t] : 0.f;
    __syncthreads();
    if (nn){
      const int cg = t & 15, rg = t >> 4;
      #pragma unroll 4
      for (int ii = 0; ii < 64; ++ii){
        const float a0 = As[rg*2][ii], a1 = As[rg*2+1][ii];
        const float4 bv = *(const float4*)&Bs[ii][cg*4];
        acc[0] += a0*bv.x; acc[1] += a0*bv.y; acc[2] += a0*bv.z; acc[3] += a0*bv.w;
        acc[4] += a1*bv.x; acc[5] += a1*bv.y; acc[6] += a1*bv.z; acc[7] += a1*bv.w;
      }
    } else {
      const int cg = t & 31, rg = t >> 5;
      #pragma unroll 4
      for (int ii = 0; ii < 64; ++ii){
        const float a0 = As[cg*2][ii], a1 = As[cg*2+1][ii];
        const float4 bv = *(const float4*)&Bs[ii][rg*4];
        acc[0] += bv.x*a0; acc[1] += bv.y*a0; acc[2] += bv.z*a0; acc[3] += bv.w*a0;
        acc[4] += bv.x*a1; acc[5] += bv.y*a1; acc[6] += bv.z*a1; acc[7] += bv.w*a1;
        if (rg == 0){ const float bb = bsv[ii]; ba0 += a0*bb; ba1 += a1*bb; }
      }
    }
    __syncthreads();
  }
  if (nn){
    const int cg = t & 15, rg = t >> 4;
    #pragma unroll
    for (int p = 0; p < 2; ++p){
      float4 o; o.x = acc[p*4]; o.y = acc[p*4+1]; o.z = acc[p*4+2]; o.w = acc[p*4+3];
      *(float4*)&C[(size_t)(rt*64 + rg*2 + p)*512 + ct*64 + cg*4] = o;
    }
  } else {
    const int cg = t & 31, rg = t >> 5;
    #pragma unroll
    for (int p = 0; p < 4; ++p){
      float2 o; o.x = acc[p]; o.y = acc[4+p];
      *(float2*)&C[(size_t)(rt*64 + rg*4 + p)*512 + ct*64 + cg*2] = o;
    }
    if (rt == 0 && rg == 0){
      float* Cb = C + 512*512;
      Cb[ct*64 + cg*2]     = ba0 + badd[ct*64 + cg*2];
      Cb[ct*64 + cg*2 + 1] = ba1 + badd[ct*64 + cg*2 + 1];
    }
  }
}

// ---------------- generic wide batched GEMV stage (FROZEN from r8) ----------------
template<int J, bool ACT, bool HASB>
__global__ __launch_bounds__(512)
void k_gemv(const float* __restrict__ WT, const float* __restrict__ X,
            const float* __restrict__ bias, float* __restrict__ Y,
            const float scale){
  const int sl = blockIdx.x, b = blockIdx.y, t = threadIdx.x;
  const int c = t & 63, w = t >> 6;
  __shared__ float xs[D_];
  __shared__ float red[8][64];
  xs[t] = X[(size_t)b*D_ + t];
  __syncthreads();
  const int j = sl*64 + c;
  const float* wp = WT + (size_t)(w*64)*J + j;
  const float* xp = xs + w*64;
  float a0=0.f, a1=0.f, a2=0.f, a3=0.f;
  #pragma unroll
  for (int k = 0; k < 64; k += 4){
    a0 += wp[(size_t)(k+0)*J] * xp[k+0];
    a1 += wp[(size_t)(k+1)*J] * xp[k+1];
    a2 += wp[(size_t)(k+2)*J] * xp[k+2];
    a3 += wp[(size_t)(k+3)*J] * xp[k+3];
  }
  red[w][c] = (a0+a1)+(a2+a3);
  __syncthreads();
  if (w == 0 && j < J){
    float s = ((red[0][c]+red[1][c])+(red[2][c]+red[3][c]))
            + ((red[4][c]+red[5][c])+(red[6][c]+red[7][c]));
    s = s * scale;
    if (HASB) s += bias[j];
    Y[(size_t)b*J + j] = ACT ? gelu_f(s) : s;
  }
}

// query head (FROZEN from r8): qv[j] = sum_k QW2qT[k][j]*gelu(xq*w1q+b1q)[k] + qbc[j]
__global__ __launch_bounds__(512)
void k_gemv_q1(const float* __restrict__ xq,  const float* __restrict__ w1q,
               const float* __restrict__ b1q,
               const float* __restrict__ WT,  const float* __restrict__ bias,
               float* __restrict__ Y){
  const int sl = blockIdx.x, b = blockIdx.y, t = threadIdx.x;
  const int c = t & 63, w = t >> 6;
  __shared__ float xs[D_];
  __shared__ float red[8][64];
  xs[t] = gelu_f(xq[b] * w1q[t] + b1q[t]);
  __syncthreads();
  const int j = sl*64 + c;
  const float* wp = WT + (size_t)(w*64)*D_ + j;
  const float* xp = xs + w*64;
  float a0=0.f, a1=0.f, a2=0.f, a3=0.f;
  #pragma unroll
  for (int k = 0; k < 64; k += 4){
    a0 += wp[(size_t)(k+0)*D_] * xp[k+0];
    a1 += wp[(size_t)(k+1)*D_] * xp[k+1];
    a2 += wp[(size_t)(k+2)*D_] * xp[k+2];
    a3 += wp[(size_t)(k+3)*D_] * xp[k+3];
  }
  red[w][c] = (a0+a1)+(a2+a3);
  __syncthreads();
  if (w == 0){
    float s = ((red[0][c]+red[1][c])+(red[2][c]+red[3][c]))
            + ((red[4][c]+red[5][c])+(red[6][c]+red[7][c]));
    Y[(size_t)b*D_ + j] = s + bias[j];
  }
}

// ---------------- main: 256 thr (4 waves), launch_bounds(256,3) ----------------
// r9 lesson: (256,2) let the allocator target 128 regs -> 88 MB scratch spill, occ 20.6%.
// (256,3) caps at 170 regs/wave: natural need ~160 fits -> no spill, 3 blocks/CU (12 waves).
// Verification signature: WRITE_SIZE 88 MB -> ~4.2 MB, OccupancyPercent -> ~31-37.
__global__ __launch_bounds__(256, 3)
void k_main(const float* __restrict__ x,                 // [B,N,DI]
            const unsigned short* __restrict__ w1p,      // packed bf16
            const float* __restrict__ b1,
            const float* __restrict__ qkw2,              // [B,D]
            float* __restrict__ part,                    // [B,NT,D]
            float* __restrict__ esum){                   // [B,NT]
  const int tile = blockIdx.x;       // 0..63
  const int b = blockIdx.y;          // 0..31
  const int t = threadIdx.x;         // 0..255
  const int lane = t & 63;
  const int wid = t >> 6;            // 0..3
  const int ln = lane & 15;
  const int q  = lane >> 4;          // 0..3

  __shared__ unsigned short x_lds[2][SN_ * XROW_];  // 2 x 4352 B
  __shared__ float s_ws[4][SN_];                    // 256 B
  __shared__ float e_lds[SN_];                      // 64 B
  __shared__ float sb1[D_];                         // 2048 B
  __shared__ float sq2[D_];                         // 2048 B

  const int jb = wid * 128;             // this wave's 128-col j block
  const unsigned short* w1base = w1p + (jb + ln)*32 + q*8;
  const float* xbase = x + ((size_t)b * N_ + tile * TN_) * DI_;

  sb1[t] = b1[t];            sb1[t+256] = b1[t+256];
  sq2[t] = qkw2[b*D_ + t];   sq2[t+256] = qkw2[b*D_ + t+256];
  {
    const float4* x4 = (const float4*)xbase;
    #pragma unroll
    for (int i = 0; i < 2; ++i){
      const int f = i*256 + t;            // 512 float4 per sub-tile
      float4 v = x4[f];
      const int m = f >> 5;
      const int k = (f & 31) << 2;
      uint2 pk;
      pk.x = pk2bf(v.x, v.y);
      pk.y = pk2bf(v.z, v.w);
      *(uint2*)&x_lds[0][m*XROW_ + k] = pk;
    }
  }
  __syncthreads();

  f4v zacc[8];
  #pragma unroll
  for (int i = 0; i < 8; ++i) zacc[i] = (f4v){0.f,0.f,0.f,0.f};
  float etot = 0.f;

  for (int s = 0; s < NSUB_; ++s){
    const unsigned short* xb = x_lds[s & 1];

    f4v acc[8];
    #pragma unroll
    for (int i = 0; i < 8; ++i) acc[i] = (f4v){0.f,0.f,0.f,0.f};

    // ---- GEMM1: h1^T[j,m] over this wave's 128 j, 16 m ----
    #pragma unroll
    for (int kk = 0; kk < 4; ++kk){
      const int k = kk*32 + q*8;
      const s8v bx = *(const s8v*)&xb[ln*XROW_ + k];
      #pragma unroll
      for (int jt = 0; jt < 8; ++jt){
        const s8v aw = *(const s8v*)(w1base + kk*(D_*32) + jt*(16*32));
        acc[jt] = __builtin_amdgcn_mfma_f32_16x16x32_bf16(aw, bx, acc[jt], 0,0,0);
      }
    }

    // ---- prefetch next sub-tile ----
    float4 pv0, pv1;
    if (s + 1 < NSUB_){
      const float4* x4 = (const float4*)(xbase + (size_t)(s+1)*SN_*DI_);
      pv0 = x4[t];
      pv1 = x4[256 + t];
    }

    // ---- bias + GELU (in place) + score partial ----
    float sp = 0.f;
    #pragma unroll
    for (int jt = 0; jt < 8; ++jt){
      const f4v bv = *(const f4v*)&sb1[jb + jt*16 + q*4];
      const f4v qv = *(const f4v*)&sq2[jb + jt*16 + q*4];
      f4v a = acc[jt];
      a[0] = gelu_f(a[0] + bv[0]);
      a[1] = gelu_f(a[1] + bv[1]);
      a[2] = gelu_f(a[2] + bv[2]);
      a[3] = gelu_f(a[3] + bv[3]);
      acc[jt] = a;
      sp += qv[0]*a[0] + qv[1]*a[1] + qv[2]*a[2] + qv[3]*a[3];
    }
    sp += __shfl_xor(sp, 16, 64);
    sp += __shfl_xor(sp, 32, 64);
    if (q == 0) s_ws[wid][ln] = sp;     // m = ln

    // ---- write prefetched x to the other buffer ----
    if (s + 1 < NSUB_){
      unsigned short* xn = &x_lds[(s+1) & 1][0];
      int f = t, m = f >> 5, k = (f & 31) << 2;
      uint2 pk;
      pk.x = pk2bf(pv0.x, pv0.y);
      pk.y = pk2bf(pv0.z, pv0.w);
      *(uint2*)&xn[m*XROW_ + k] = pk;
      f = 256 + t; m = f >> 5; k = (f & 31) << 2;
      pk.x = pk2bf(pv1.x, pv1.y);
      pk.y = pk2bf(pv1.z, pv1.w);
      *(uint2*)&xn[m*XROW_ + k] = pk;
    }
    __syncthreads();     // (A)

    if (t < SN_){
      float sc = 0.f;
      #pragma unroll
      for (int w = 0; w < 4; ++w) sc += s_ws[w][t];
      e_lds[t] = __expf(sc);
    }
    __syncthreads();     // (B)

    if (wid == 0){
      float v = (lane < SN_) ? e_lds[lane] : 0.f;
      etot += wsum64(v);
    }

    {
      const float em = e_lds[ln];
      #pragma unroll
      for (int jt = 0; jt < 8; ++jt){
        const f4v a = acc[jt];
        #pragma unroll
        for (int r = 0; r < 4; ++r)
          zacc[jt][r] += em * a[r];
      }
    }
  }

  if (t == 0) esum[b*NT_ + tile] = etot;

  #pragma unroll
  for (int jt = 0; jt < 8; ++jt){
    #pragma unroll
    for (int r = 0; r < 4; ++r){
      float v = zacc[jt][r];
      v += __shfl_xor(v, 1, 64);
      v += __shfl_xor(v, 2, 64);
      v += __shfl_xor(v, 4, 64);
      v += __shfl_xor(v, 8, 64);
      zacc[jt][r] = v;
    }
    if (ln == 0){
      float4 o; o.x = zacc[jt][0]; o.y = zacc[jt][1]; o.z = zacc[jt][2]; o.w = zacc[jt][3];
      *(float4*)&part[((size_t)(b*NT_ + tile))*D_ + jb + jt*16 + q*4] = o;
    }
  }
}

// ---------------- fused u-reduce + VW2 gemv: grid (8,32) x 512 ----------------
// Each block redundantly builds u[b][*] (131 KB coalesced column reads of part),
// then dots its 64-col VW2T slice. Removes the separate k_fu launch.
__global__ __launch_bounds__(512)
void k_fz2(const float* __restrict__ part, const float* __restrict__ esum,
           const float* __restrict__ VW2T, float* __restrict__ zb){
  const int sl = blockIdx.x, b = blockIdx.y, t = threadIdx.x;
  const int c = t & 63, w = t >> 6;
  __shared__ float xs[D_];
  __shared__ float red[8][64];
  float p = esum[b*NT_ + (t & 63)];
  p = wsum64(p);
  const float linv = 1.0f / p;
  {
    const float* pb = part + (size_t)b*NT_*D_ + t;
    float s = 0.f;
    #pragma unroll 8
    for (int tl = 0; tl < NT_; ++tl) s += pb[tl*D_];
    xs[t] = s * linv;
  }
  __syncthreads();
  const int j = sl*64 + c;
  const float* wp = VW2T + (size_t)(w*64)*D_ + j;
  const float* xp = xs + w*64;
  float a0=0.f, a1=0.f, a2=0.f, a3=0.f;
  #pragma unroll
  for (int k = 0; k < 64; k += 4){
    a0 += wp[(size_t)(k+0)*D_] * xp[k+0];
    a1 += wp[(size_t)(k+1)*D_] * xp[k+1];
    a2 += wp[(size_t)(k+2)*D_] * xp[k+2];
    a3 += wp[(size_t)(k+3)*D_] * xp[k+3];
  }
  red[w][c] = (a0+a1)+(a2+a3);
  __syncthreads();
  if (w == 0){
    float s = ((red[0][c]+red[1][c])+(red[2][c]+red[3][c]))
            + ((red[4][c]+red[5][c])+(red[6][c]+red[7][c]));
    zb[(size_t)b*D_ + j] = s + VW2T[512*512 + j];   // folded bias zc
  }
}

extern "C" void kernel_launch(void* const* d_in, const int* in_sizes, int n_in,
                              void* d_out, int out_size, void* d_ws, size_t ws_size,
                              hipStream_t stream) {
  (void)in_sizes; (void)n_in; (void)out_size; (void)ws_size;
  const float* x_items  = (const float*)d_in[0];
  const float* x_query  = (const float*)d_in[1];
  const float* psi_x_w1 = (const float*)d_in[2];
  const float* psi_x_b1 = (const float*)d_in[3];
  const float* psi_x_w2 = (const float*)d_in[4];
  const float* psi_x_b2 = (const float*)d_in[5];
  const float* psi_q_w1 = (const float*)d_in[6];
  const float* psi_q_b1 = (const float*)d_in[7];
  const float* psi_q_w2 = (const float*)d_in[8];
  const float* psi_q_b2 = (const float*)d_in[9];
  const float* q_w      = (const float*)d_in[10];
  const float* q_b      = (const float*)d_in[11];
  const float* k_w      = (const float*)d_in[12];
  // k_b (d_in[13]) unused: constant score shift cancels in softmax
  const float* v_w      = (const float*)d_in[14];
  const float* v_b      = (const float*)d_in[15];
  const float* phi_w1   = (const float*)d_in[16];
  const float* phi_b1   = (const float*)d_in[17];
  const float* phi_w2   = (const float*)d_in[18];
  const float* phi_b2   = (const float*)d_in[19];
  float* out = (float*)d_out;

  // Workspace layout identical to r9 (proven; max end 10,645,504 B).
  char* ws = (char*)d_ws;
  unsigned short* w1p = (unsigned short*)(ws);                 // 131072
  float* qkw2  = (float*)(ws + 131072);                        // 65536
  float* part  = (float*)(ws + 196608);                        // 4194304
  float* qvg   = (float*)(ws + 196608);                        // 65536 (alias: part)
  float* esum  = (float*)(ws + 4390912);                       // 8192
  float* KW2   = (float*)(ws + 4399104);                       // 1048576
  float* zb    = (float*)(ws + 4464640);                       // 65536 (alias: KW2)
  float* hb    = (float*)(ws + 4530176);                       // 65536 (alias: KW2)
  float* QW2qT = (float*)(ws + 5447680);                       // 1050624 ([513][512])
  float* VW2T  = (float*)(ws + 6498304);                       // 1050624 ([513][512])
  float* pw1T  = (float*)(ws + 7548928);                       // 1048576
  float* pw2T  = (float*)(ws + 8597504);                       // 2048000

  const float SC = 0.04419417382415922f;   // 512^-0.5

  hipLaunchKernelGGL(k_prep3, dim3(512), dim3(512), 0, stream,
                     psi_x_w1, w1p, phi_w1, pw1T, phi_w2, pw2T,
                     k_w, psi_x_w2, KW2,
                     q_w, psi_q_w2, psi_q_b2, q_b, QW2qT,
                     v_w, psi_x_b2, v_b, VW2T);
  hipLaunchKernelGGL(k_gemv_q1, dim3(8, 32), dim3(512), 0, stream,
                     x_query, psi_q_w1, psi_q_b1, QW2qT, QW2qT + 512*512, qvg);
  hipLaunchKernelGGL(HIP_KERNEL_NAME(k_gemv<D_, false, false>), dim3(8, 32), dim3(512), 0, stream,
                     KW2, qvg, q_b /*unused*/, qkw2, SC);
  hipLaunchKernelGGL(k_main, dim3(NT_, B_), dim3(256), 0, stream,
                     x_items, w1p, psi_x_b1, qkw2, part, esum);
  hipLaunchKernelGGL(k_fz2, dim3(8, 32), dim3(512), 0, stream,
                     part, esum, VW2T, zb);
  hipLaunchKernelGGL(HIP_KERNEL_NAME(k_gemv<D_, true, true>), dim3(8, 32), dim3(512), 0, stream,
                     pw1T, zb, phi_b1, hb, 1.0f);
  hipLaunchKernelGGL(HIP_KERNEL_NAME(k_gemv<NC_, false, true>), dim3(16, 32), dim3(512), 0, stream,
                     pw2T, hb, phi_b2, out, 1.0f);
}

// Round 12
// 398.841 us; speedup vs baseline: 1.4908x; 1.4908x over previous
//
#include <hip/hip_runtime.h>
#include <hip/hip_bf16.h>

#define B_ 32
#define N_ 8192
#define DI_ 128
#define D_ 512
#define NC_ 1000
#define TN_ 128          // items per output tile (per block)
#define SN_ 16           // items per sub-tile (halved: fits 128-reg occupancy quantum)
#define NSUB_ 8          // sub-tiles per block
#define NT_ 64           // tiles = N_/TN_
#define XROW_ 136        // x_lds row stride in shorts (pad +8)

typedef short s8v __attribute__((ext_vector_type(8)));
typedef float f4v __attribute__((ext_vector_type(4)));

__device__ __forceinline__ unsigned short f2bf(float f){
  union { float f; unsigned u; } c; c.f = f;
  unsigned r = c.u + 0x7fffu + ((c.u >> 16) & 1u);
  return (unsigned short)(r >> 16);
}

// hardware v_cvt_pk_bf16_f32: 2 floats -> packed bf16 (RNE), a in low 16
__device__ __forceinline__ unsigned pk2bf(float a, float b){
  float2 f; f.x = a; f.y = b;
  __hip_bfloat162 h = __float22bfloat162_rn(f);
  union { __hip_bfloat162 h; unsigned u; } c; c.h = h;
  return c.u;
}

// exact GELU: 0.5x(1+erf(x/sqrt2)); Abramowitz-Stegun 7.1.26, |err| <= 1.5e-7
__device__ __forceinline__ float gelu_f(float x){
  float ax = fabsf(x) * 0.70710678118654752f;
  float t = __builtin_amdgcn_rcpf(1.0f + 0.3275911f * ax);
  float poly = ((((1.061405429f*t - 1.453152027f)*t + 1.421413741f)*t
                 - 0.284496736f)*t + 0.254829592f)*t;
  float e = __expf(-ax*ax);
  float erf_ax = 1.0f - poly*e;
  erf_ax = (x >= 0.0f) ? erf_ax : -erf_ax;
  return 0.5f * x * (1.0f + erf_ax);
}

__device__ __forceinline__ float wsum64(float v){
  #pragma unroll
  for (int off = 32; off; off >>= 1) v += __shfl_xor(v, off, 64);
  return v;
}

// ---------------- prep: w1 bf16 pack + transpose 6 tail/query weight matrices (FROZEN r5/r8) ----------------
__global__ __launch_bounds__(512)
void k_prep2(const float* __restrict__ w1, unsigned short* __restrict__ w1p,
             const float* __restrict__ sw0, float* __restrict__ dt0,   // psi_x_w2 -> w2T
             const float* __restrict__ sw1, float* __restrict__ dt1,   // v_w     -> vwT
             const float* __restrict__ sw2, float* __restrict__ dt2,   // phi_w1  -> pw1T
             const float* __restrict__ sw3, float* __restrict__ dt3,   // psi_q_w2-> w2qT
             const float* __restrict__ sw4, float* __restrict__ dt4,   // q_w     -> qwT
             const float* __restrict__ pw2, float* __restrict__ pw2T){
  const int t = threadIdx.x;
  const int bid = blockIdx.x;
  if (bid < 128){
    const int i = bid*512 + t;                 // < 65536 = D_*DI_
    const int j = i / DI_, kc = i % DI_;
    const int kk = kc >> 5, q = (kc >> 3) & 3, s = kc & 7;
    w1p[((kk*D_ + j)*4 + q)*8 + s] = f2bf(w1[i]);
    return;
  }
  __shared__ float tile[64][65];
  const int r0 = t >> 6;                       // 0..7
  const int c  = t & 63;
  if (bid < 448){
    const int id = bid - 128;
    const int mi = id >> 6;                    // matrix 0..4
    const int tt = id & 63;
    const int to = tt >> 3, tk = tt & 7;
    const float* src = mi==0?sw0: mi==1?sw1: mi==2?sw2: mi==3?sw3: sw4;
    float*       dst = mi==0?dt0: mi==1?dt1: mi==2?dt2: mi==3?dt3: dt4;
    #pragma unroll
    for (int i = 0; i < 8; ++i){
      const int r = r0 + i*8;
      tile[r][c] = src[(size_t)(to*64 + r)*D_ + tk*64 + c];
    }
    __syncthreads();
    #pragma unroll
    for (int i = 0; i < 8; ++i){
      const int r = r0 + i*8;
      dst[(size_t)(tk*64 + r)*D_ + to*64 + c] = tile[c][r];
    }
  } else {
    const int id = bid - 448;                  // 0..127
    const int tr = id >> 3, tk = id & 7;
    #pragma unroll
    for (int i = 0; i < 8; ++i){
      const int r = r0 + i*8;
      const int ro = tr*64 + r;
      tile[r][c] = (ro < NC_) ? pw2[(size_t)ro*D_ + tk*64 + c] : 0.f;
    }
    __syncthreads();
    #pragma unroll
    for (int i = 0; i < 8; ++i){
      const int r = r0 + i*8;
      const int co = tr*64 + c;
      if (co < NC_)
        pw2T[(size_t)(tk*64 + r)*NC_ + co] = tile[c][r];
    }
  }
}

// ---------------- generic wide batched GEMV stage (FROZEN r8) ----------------
template<int J, bool ACT, bool HASB>
__global__ __launch_bounds__(512)
void k_gemv(const float* __restrict__ WT, const float* __restrict__ X,
            const float* __restrict__ bias, float* __restrict__ Y,
            const float scale){
  const int sl = blockIdx.x, b = blockIdx.y, t = threadIdx.x;
  const int c = t & 63, w = t >> 6;
  __shared__ float xs[D_];
  __shared__ float red[8][64];
  xs[t] = X[(size_t)b*D_ + t];
  __syncthreads();
  const int j = sl*64 + c;
  const float* wp = WT + (size_t)(w*64)*J + j;
  const float* xp = xs + w*64;
  float a0=0.f, a1=0.f, a2=0.f, a3=0.f;
  #pragma unroll
  for (int k = 0; k < 64; k += 4){
    a0 += wp[(size_t)(k+0)*J] * xp[k+0];
    a1 += wp[(size_t)(k+1)*J] * xp[k+1];
    a2 += wp[(size_t)(k+2)*J] * xp[k+2];
    a3 += wp[(size_t)(k+3)*J] * xp[k+3];
  }
  red[w][c] = (a0+a1)+(a2+a3);
  __syncthreads();
  if (w == 0 && j < J){
    float s = ((red[0][c]+red[1][c])+(red[2][c]+red[3][c]))
            + ((red[4][c]+red[5][c])+(red[6][c]+red[7][c]));
    s = s * scale;
    if (HASB) s += bias[j];
    Y[(size_t)b*J + j] = ACT ? gelu_f(s) : s;
  }
}

// query stage 1 (FROZEN r8): X built on the fly: xs[k] = gelu(xq[b]*w1q[k]+b1q[k])
__global__ __launch_bounds__(512)
void k_gemv_q1(const float* __restrict__ xq,  const float* __restrict__ w1q,
               const float* __restrict__ b1q,
               const float* __restrict__ WT,  const float* __restrict__ bias,
               float* __restrict__ Y){
  const int sl = blockIdx.x, b = blockIdx.y, t = threadIdx.x;
  const int c = t & 63, w = t >> 6;
  __shared__ float xs[D_];
  __shared__ float red[8][64];
  xs[t] = gelu_f(xq[b] * w1q[t] + b1q[t]);
  __syncthreads();
  const int j = sl*64 + c;
  const float* wp = WT + (size_t)(w*64)*D_ + j;
  const float* xp = xs + w*64;
  float a0=0.f, a1=0.f, a2=0.f, a3=0.f;
  #pragma unroll
  for (int k = 0; k < 64; k += 4){
    a0 += wp[(size_t)(k+0)*D_] * xp[k+0];
    a1 += wp[(size_t)(k+1)*D_] * xp[k+1];
    a2 += wp[(size_t)(k+2)*D_] * xp[k+2];
    a3 += wp[(size_t)(k+3)*D_] * xp[k+3];
  }
  red[w][c] = (a0+a1)+(a2+a3);
  __syncthreads();
  if (w == 0){
    float s = ((red[0][c]+red[1][c])+(red[2][c]+red[3][c]))
            + ((red[4][c]+red[5][c])+(red[6][c]+red[7][c]));
    Y[(size_t)b*D_ + j] = s + bias[j];
  }
}

// ---------------- main: 8 waves x 64 j-cols, SN=16 (acc[4]+zacc[4] = 32 regs) ----------------
// Occupancy is HW-quantized at 64/128/256 regs/wave (r3=140regs->2w/SIMD, r10 proved no
// 3w/SIMD step). This working set (~100 regs) fits the 128 quantum -> (512,4) without spill
// -> 2 blocks/CU, 4 waves/SIMD. Verification: WRITE_SIZE stays ~4.2 MB, Occupancy ~40-45%.
__global__ __launch_bounds__(512, 4)
void k_main(const float* __restrict__ x,                 // [B,N,DI]
            const unsigned short* __restrict__ w1p,      // packed bf16
            const float* __restrict__ b1,
            const float* __restrict__ qkw2,              // [B,D]
            float* __restrict__ part,                    // [B,NT,D]
            float* __restrict__ esum){                   // [B,NT]
  const int tile = blockIdx.x;       // 0..63
  const int b = blockIdx.y;          // 0..31
  const int t = threadIdx.x;         // 0..511
  const int lane = t & 63;
  const int wid = t >> 6;            // 0..7
  const int ln = lane & 15;
  const int q  = lane >> 4;          // 0..3

  __shared__ unsigned short x_lds[2][SN_ * XROW_];  // 2 x 4352 B
  __shared__ float s_ws[8][SN_];                    // 512 B
  __shared__ float e_lds[SN_];                      // 64 B
  __shared__ float sb1[D_];                         // 2048 B
  __shared__ float sq2[D_];                         // 2048 B

  const int jb = wid * 64;              // this wave's 64-col j block
  const unsigned short* w1base = w1p + (jb + ln)*32 + q*8;
  const float* xbase = x + ((size_t)b * N_ + tile * TN_) * DI_;

  sb1[t] = b1[t];
  sq2[t] = qkw2[b*D_ + t];
  {
    const float4* x4 = (const float4*)xbase;
    float4 v = x4[t];                   // 512 float4 = sub-tile 0 (16 rows x 32)
    const int m = t >> 5;
    const int k = (t & 31) << 2;
    uint2 pk;
    pk.x = pk2bf(v.x, v.y);
    pk.y = pk2bf(v.z, v.w);
    *(uint2*)&x_lds[0][m*XROW_ + k] = pk;
  }
  __syncthreads();

  f4v zacc[4];
  #pragma unroll
  for (int i = 0; i < 4; ++i) zacc[i] = (f4v){0.f,0.f,0.f,0.f};
  float etot = 0.f;

  for (int s = 0; s < NSUB_; ++s){
    const unsigned short* xb = x_lds[s & 1];

    f4v acc[4];
    #pragma unroll
    for (int i = 0; i < 4; ++i) acc[i] = (f4v){0.f,0.f,0.f,0.f};

    // ---- GEMM1: h1^T[j,m] over this wave's 64 j, 16 m ----
    #pragma unroll
    for (int kk = 0; kk < 4; ++kk){
      const int k = kk*32 + q*8;
      const s8v bx = *(const s8v*)&xb[ln*XROW_ + k];
      #pragma unroll
      for (int jt = 0; jt < 4; ++jt){
        const s8v aw = *(const s8v*)(w1base + kk*(D_*32) + jt*(16*32));
        acc[jt] = __builtin_amdgcn_mfma_f32_16x16x32_bf16(aw, bx, acc[jt], 0,0,0);
      }
    }

    // ---- prefetch next sub-tile (1 float4/thread) ----
    float4 pv0 = make_float4(0.f, 0.f, 0.f, 0.f);
    if (s + 1 < NSUB_)
      pv0 = ((const float4*)(xbase + (size_t)(s+1)*SN_*DI_))[t];

    // ---- bias + exact GELU (in place) + score partial over this wave's 64 j ----
    float sp = 0.f;
    #pragma unroll
    for (int jt = 0; jt < 4; ++jt){
      const f4v bv = *(const f4v*)&sb1[jb + jt*16 + q*4];
      const f4v qv = *(const f4v*)&sq2[jb + jt*16 + q*4];
      f4v a = acc[jt];
      a[0] = gelu_f(a[0] + bv[0]);
      a[1] = gelu_f(a[1] + bv[1]);
      a[2] = gelu_f(a[2] + bv[2]);
      a[3] = gelu_f(a[3] + bv[3]);
      acc[jt] = a;
      sp += qv[0]*a[0] + qv[1]*a[1] + qv[2]*a[2] + qv[3]*a[3];
    }
    sp += __shfl_xor(sp, 16, 64);
    sp += __shfl_xor(sp, 32, 64);
    if (q == 0) s_ws[wid][ln] = sp;     // m = ln

    // ---- write prefetched x to the other buffer ----
    if (s + 1 < NSUB_){
      unsigned short* xn = &x_lds[(s+1) & 1][0];
      const int m = t >> 5;
      const int k = (t & 31) << 2;
      uint2 pk;
      pk.x = pk2bf(pv0.x, pv0.y);
      pk.y = pk2bf(pv0.z, pv0.w);
      *(uint2*)&xn[m*XROW_ + k] = pk;
    }
    __syncthreads();     // (A) scores + staging complete

    if (t < SN_){
      float sc = 0.f;
      #pragma unroll
      for (int w = 0; w < 8; ++w) sc += s_ws[w][t];
      e_lds[t] = __expf(sc);     // constant shift cancels in softmax
    }
    __syncthreads();     // (B) e ready

    if (wid == 0){
      float v = (lane < SN_) ? e_lds[lane] : 0.f;
      etot += wsum64(v);
    }

    // ---- weighted hbar accumulate ----
    {
      const float em = e_lds[ln];
      #pragma unroll
      for (int jt = 0; jt < 4; ++jt){
        const f4v a = acc[jt];
        #pragma unroll
        for (int r = 0; r < 4; ++r)
          zacc[jt][r] += em * a[r];
      }
    }
    // no barrier needed: next iter's e_lds write is after its own barrier (A)
  }

  if (t == 0) esum[b*NT_ + tile] = etot;

  // reduce zacc over ln lanes (same q => same j set), write float4 per q-lane
  #pragma unroll
  for (int jt = 0; jt < 4; ++jt){
    #pragma unroll
    for (int r = 0; r < 4; ++r){
      float v = zacc[jt][r];
      v += __shfl_xor(v, 1, 64);
      v += __shfl_xor(v, 2, 64);
      v += __shfl_xor(v, 4, 64);
      v += __shfl_xor(v, 8, 64);
      zacc[jt][r] = v;
    }
    if (ln == 0){
      float4 o; o.x = zacc[jt][0]; o.y = zacc[jt][1]; o.z = zacc[jt][2]; o.w = zacc[jt][3];
      *(float4*)&part[((size_t)(b*NT_ + tile))*D_ + jb + jt*16 + q*4] = o;
    }
  }
}

// u[b][col] = (1/sum e) * sum_tl part[b][tl][col];  grid (32,4) x 128  (FROZEN r8)
__global__ __launch_bounds__(128)
void k_fu(const float* __restrict__ part, const float* __restrict__ esum,
          float* __restrict__ u){
  const int b = blockIdx.x, sl = blockIdx.y, t = threadIdx.x;
  float p = esum[b*NT_ + (t & 63)];
  p = wsum64(p);
  const float linv = 1.0f / p;
  const int col = sl*128 + t;
  const float* pb = part + (size_t)b*NT_*D_ + col;
  float s = 0.f;
  #pragma unroll 8
  for (int tl = 0; tl < NT_; ++tl) s += pb[tl*D_];
  u[b*D_ + col] = s * linv;
}

extern "C" void kernel_launch(void* const* d_in, const int* in_sizes, int n_in,
                              void* d_out, int out_size, void* d_ws, size_t ws_size,
                              hipStream_t stream) {
  (void)in_sizes; (void)n_in; (void)out_size; (void)ws_size;
  const float* x_items  = (const float*)d_in[0];
  const float* x_query  = (const float*)d_in[1];
  const float* psi_x_w1 = (const float*)d_in[2];
  const float* psi_x_b1 = (const float*)d_in[3];
  const float* psi_x_w2 = (const float*)d_in[4];
  const float* psi_x_b2 = (const float*)d_in[5];
  const float* psi_q_w1 = (const float*)d_in[6];
  const float* psi_q_b1 = (const float*)d_in[7];
  const float* psi_q_w2 = (const float*)d_in[8];
  const float* psi_q_b2 = (const float*)d_in[9];
  const float* q_w      = (const float*)d_in[10];
  const float* q_b      = (const float*)d_in[11];
  const float* k_w      = (const float*)d_in[12];
  // k_b (d_in[13]) unused: constant score shift cancels in softmax
  const float* v_w      = (const float*)d_in[14];
  const float* v_b      = (const float*)d_in[15];
  const float* phi_w1   = (const float*)d_in[16];
  const float* phi_b1   = (const float*)d_in[17];
  const float* phi_w2   = (const float*)d_in[18];
  const float* phi_b2   = (const float*)d_in[19];
  float* out = (float*)d_out;

  // Workspace layout: identical to r8 (proven; max end 11,739,136 B).
  char* ws = (char*)d_ws;
  unsigned short* w1p = (unsigned short*)(ws);                 // 131072
  float* qkw2 = (float*)(ws + 131072);                         // 65536
  float* part = (float*)(ws + 196608);                         // 4194304
  float* h2g  = (float*)(ws + 196608);                         // 65536  (alias: part)
  float* qvg  = (float*)(ws + 262144);                         // 65536  (alias: part)
  float* qkg  = (float*)(ws + 327680);                         // 65536  (alias: part)
  float* esum = (float*)(ws + 4390912);                        // 8192
  float* w2T  = (float*)(ws + 4399104);                        // 1048576
  float* vwT  = (float*)(ws + 5447680);                        // 1048576
  float* pw1T = (float*)(ws + 6496256);                        // 1048576
  float* w2qT = (float*)(ws + 7544832);                        // 1048576
  float* ub   = (float*)(ws + 7544832);                        // 65536  (alias: w2qT)
  float* u2b  = (float*)(ws + 7610368);                        // 65536  (alias: w2qT)
  float* zb   = (float*)(ws + 7675904);                        // 65536  (alias: w2qT)
  float* hb   = (float*)(ws + 7741440);                        // 65536  (alias: w2qT)
  float* qwT  = (float*)(ws + 8593408);                        // 1048576
  float* pw2T = (float*)(ws + 9641984);                        // 2097152 (2048000 used + pad)

  const float SC = 0.04419417382415922f;   // 512^-0.5

  hipLaunchKernelGGL(k_prep2, dim3(576), dim3(512), 0, stream,
                     psi_x_w1, w1p,
                     psi_x_w2, w2T, v_w, vwT, phi_w1, pw1T,
                     psi_q_w2, w2qT, q_w, qwT, phi_w2, pw2T);
  hipLaunchKernelGGL(k_gemv_q1, dim3(8, 32), dim3(512), 0, stream,
                     x_query, psi_q_w1, psi_q_b1, w2qT, psi_q_b2, h2g);
  hipLaunchKernelGGL(HIP_KERNEL_NAME(k_gemv<D_, false, true>), dim3(8, 32), dim3(512), 0, stream,
                     qwT, h2g, q_b, qvg, 1.0f);
  hipLaunchKernelGGL(HIP_KERNEL_NAME(k_gemv<D_, false, false>), dim3(8, 32), dim3(512), 0, stream,
                     k_w, qvg, q_b /*unused*/, qkg, SC);
  hipLaunchKernelGGL(HIP_KERNEL_NAME(k_gemv<D_, false, false>), dim3(8, 32), dim3(512), 0, stream,
                     psi_x_w2, qkg, q_b /*unused*/, qkw2, 1.0f);
  hipLaunchKernelGGL(k_main, dim3(NT_, B_), dim3(512), 0, stream,
                     x_items, w1p, psi_x_b1, qkw2, part, esum);
  hipLaunchKernelGGL(k_fu, dim3(32, 4), dim3(128), 0, stream,
                     part, esum, ub);
  hipLaunchKernelGGL(HIP_KERNEL_NAME(k_gemv<D_, false, true>), dim3(8, 32), dim3(512), 0, stream,
                     w2T, ub, psi_x_b2, u2b, 1.0f);
  hipLaunchKernelGGL(HIP_KERNEL_NAME(k_gemv<D_, false, true>), dim3(8, 32), dim3(512), 0, stream,
                     vwT, u2b, v_b, zb, 1.0f);
  hipLaunchKernelGGL(HIP_KERNEL_NAME(k_gemv<D_, true, true>), dim3(8, 32), dim3(512), 0, stream,
                     pw1T, zb, phi_b1, hb, 1.0f);
  hipLaunchKernelGGL(HIP_KERNEL_NAME(k_gemv<NC_, false, true>), dim3(16, 32), dim3(512), 0, stream,
                     pw2T, hb, phi_b2, out, 1.0f);
}